// Round 10
// baseline (565.581 us; speedup 1.0000x reference)
//
#include <hip/hip_runtime.h>
#include <hip/hip_cooperative_groups.h>
#include <stdint.h>

namespace cg = cooperative_groups;

// ---- problem constants (fixed by setup_inputs) ----
constexpr int NB   = 2;       // batch
constexpr int NN   = 13824;   // nodes = 6*48*48
constexpr int NE   = 55296;   // edges = 4*NN
constexpr int H    = 32;      // node hidden
constexpr int EHID = 64;      // edge hidden
constexpr int HH   = 1024;    // H*H
constexpr int TILE = 2304;    // 48*48 nodes per tile
constexpr int NXC  = 48;

typedef float f32x4 __attribute__((ext_vector_type(4)));
typedef short s16x8 __attribute__((ext_vector_type(8)));
typedef unsigned int u32x2 __attribute__((ext_vector_type(2)));
typedef unsigned int u32x4 __attribute__((ext_vector_type(4)));
typedef __attribute__((address_space(3))) unsigned int as3_uint;

static __device__ __forceinline__ unsigned short f2bf(float f) {
    unsigned u = __float_as_uint(f);
    return (unsigned short)((u + 0x7fffu + ((u >> 16) & 1u)) >> 16);
}
static __device__ __forceinline__ unsigned packbf(float lo, float hi) {
    return (unsigned)f2bf(lo) | ((unsigned)f2bf(hi) << 16);
}
static __device__ __forceinline__ float sigf(float v) {
    return 1.0f / (1.0f + __expf(-v));
}
static __device__ __forceinline__ float tanhfast(float v) {
    return 1.0f - 2.0f / (1.0f + __expf(2.0f * v));
}

// ---- fused pre-pass: aB | BpT | node projection | GRU weight bf16 ----
__global__ void __launch_bounds__(256)
k_pre(const float* __restrict__ ef, const float* __restrict__ eW1,
      const float* __restrict__ eb1, unsigned short* __restrict__ aB,
      const float* __restrict__ eW2, const float* __restrict__ eb2,
      unsigned short* __restrict__ BpT, float* __restrict__ eb2p,
      const float* __restrict__ in, const float* __restrict__ pW1,
      const float* __restrict__ pb1, const float* __restrict__ pW2,
      const float* __restrict__ pb2, float* __restrict__ S0,
      unsigned short* __restrict__ xb0,
      const float* __restrict__ gWih, const float* __restrict__ gWhh,
      unsigned short* __restrict__ gWb) {
    int blk = blockIdx.x;
    if (blk < 3456) {              // aB[e][k] = relu(ef@eW1+eb1) bf16, 4 k per thread
        int t = blk * 256 + threadIdx.x;
        int e = t >> 4, kq = (t & 15) * 4;
        float f0 = ef[e * 2], f1 = ef[e * 2 + 1];
        u32x2 w;
#pragma unroll
        for (int q = 0; q < 2; q++) {
            int k = kq + q * 2;
            float v0 = fmaxf(f0 * eW1[k]     + f1 * eW1[64 + k]     + eb1[k],     0.f);
            float v1 = fmaxf(f0 * eW1[k + 1] + f1 * eW1[64 + k + 1] + eb1[k + 1], 0.f);
            w[q] = packbf(v0, v1);
        }
        *(u32x2*)(aB + e * 64 + kq) = w;
    } else if (blk < 3520) {       // BpT[j'][k] = eW2[k][perm(j')]
        int t = (blk - 3456) * 256 + threadIdx.x;   // 16384 threads
        int jp = t >> 4, kq = (t & 15) * 4;
        int src_col = (jp & 31) * 32 + (jp >> 5);
        u32x2 w;
#pragma unroll
        for (int q = 0; q < 2; q++) {
            int k = kq + q * 2;
            w[q] = packbf(eW2[k * HH + src_col], eW2[(k + 1) * HH + src_col]);
        }
        *(u32x2*)(BpT + jp * 64 + kq) = w;
        if (kq == 0) eb2p[jp] = eb2[src_col];
    } else if (blk < 6976) {       // node projection
        int t = (blk - 3520) * 256 + threadIdx.x;
        int p = t >> 5;            // row m = b*NN + n
        int l = t & 31;
        float iv = (l < 16) ? in[p * 16 + l] : 0.f;
        float hid = pb1[l];
#pragma unroll
        for (int c = 0; c < 16; c++) hid = fmaf(__shfl(iv, c, 32), pW1[c * H + l], hid);
        hid = fmaxf(hid, 0.f);
        float out = pb2[l];
#pragma unroll
        for (int h = 0; h < 32; h++) out = fmaf(__shfl(hid, h, 32), pW2[h * H + l], out);
        S0[p * H + l]  = out;
        xb0[p * H + l] = f2bf(out);
    } else {                       // GRU weights: [96][32] Wih | [96][32] Whh
        int idx = (blk - 6976) * 256 + threadIdx.x;    // [0, 6144)
        gWb[idx] = f2bf(idx < 3072 ? gWih[idx] : gWhh[idx - 3072]);
    }
}

// ---- We GEMM (swapped operands): A = BpT (j' rows), B = aB (e rows) ----
// Output rows PERMUTED to node-major: WeTn[(n*4+k)][o*32+h] bf16.
__global__ void __launch_bounds__(256)
k_gemm(const unsigned short* __restrict__ Bp, const unsigned short* __restrict__ Ae,
       const float* __restrict__ eb2p, unsigned short* __restrict__ C) {
    __shared__ unsigned char lds[32768] __attribute__((aligned(16)));
    const int tid  = threadIdx.x;
    const int wv   = tid >> 6;
    const int lane = tid & 63;
    const int lr   = lane & 15;
    const int lg   = lane >> 4;
    const int jbt  = blockIdx.x;  // j' tile 0..7
    const int ebt  = blockIdx.y;  // e tile 0..431

    const unsigned char* Ag = (const unsigned char*)Bp + (size_t)jbt * 16384;
    const unsigned char* Bg = (const unsigned char*)Ae + (size_t)ebt * 16384;

#pragma unroll
    for (int c = 0; c < 4; c++) {
        int fbase = (wv * 4 + c) * 1024;
        int f  = fbase + lane * 16;
        int sw = f ^ (((f >> 7) & 7) << 4);
        __builtin_amdgcn_global_load_lds(
            (const __attribute__((address_space(1))) unsigned int*)(Ag + sw),
            (as3_uint*)(lds + fbase), 16, 0, 0);
        __builtin_amdgcn_global_load_lds(
            (const __attribute__((address_space(1))) unsigned int*)(Bg + sw),
            (as3_uint*)(lds + 16384 + fbase), 16, 0, 0);
    }
    asm volatile("s_waitcnt vmcnt(0)" ::: "memory");
    __syncthreads();

    const int wm = wv >> 1, wn = wv & 1;
    f32x4 acc[4][4] = {};
#pragma unroll
    for (int kk = 0; kk < 2; kk++) {
        s16x8 af[4], bf[4];
#pragma unroll
        for (int i = 0; i < 4; i++) {
            int la = ((wm * 64 + i * 16 + lr) * 64 + kk * 32 + lg * 8) * 2;
            la ^= ((la >> 7) & 7) << 4;
            af[i] = *(const s16x8*)(lds + la);
            int lb = ((wn * 64 + i * 16 + lr) * 64 + kk * 32 + lg * 8) * 2;
            lb ^= ((lb >> 7) & 7) << 4;
            bf[i] = *(const s16x8*)(lds + 16384 + lb);
        }
#pragma unroll
        for (int i = 0; i < 4; i++)
#pragma unroll
            for (int j = 0; j < 4; j++)
                acc[i][j] = __builtin_amdgcn_mfma_f32_16x16x32_bf16(af[i], bf[j], acc[i][j], 0, 0, 0);
    }

    float bias[4][4];
#pragma unroll
    for (int i = 0; i < 4; i++)
#pragma unroll
        for (int r = 0; r < 4; r++)
            bias[i][r] = eb2p[jbt * 128 + wm * 64 + i * 16 + lg * 4 + r];

    __syncthreads();   // reuse lds as C tile [e_local 128][j' 128] bf16
#pragma unroll
    for (int i = 0; i < 4; i++) {
#pragma unroll
        for (int j = 0; j < 4; j++) {
            int el    = wn * 64 + j * 16 + lr;
            int jbase = wm * 64 + i * 16 + lg * 4;
            int L0 = el * 256 + jbase * 2;
            int ph = L0 ^ ((el & 7) << 4);
            u32x2 w;
            w[0] = packbf(acc[i][j][0] + bias[i][0], acc[i][j][1] + bias[i][1]);
            w[1] = packbf(acc[i][j][2] + bias[i][2], acc[i][j][3] + bias[i][3]);
            *(u32x2*)(lds + ph) = w;
        }
    }
    __syncthreads();

    // node-major permuted write: e = q*TILE + i0 + el, q = t*4+k
    const int q  = (ebt * 128) / TILE;      // TILE = 18*128
    const int i0 = (ebt * 128) % TILE;
    const int tt = q >> 2, kk2 = q & 3;
    const size_t nbase = (size_t)tt * TILE + i0;
#pragma unroll
    for (int pass = 0; pass < 8; pass++) {
        int L2 = pass * 4096 + tid * 16;
        int el = L2 >> 8;
        int ph = L2 ^ ((el & 7) << 4);
        u32x4 v = *(const u32x4*)(lds + ph);
        size_t drow = (nbase + el) * 4 + kk2;
        *(u32x4*)((unsigned char*)C + drow * 2048 + (size_t)jbt * 256 + (L2 & 255)) = v;
    }
}

// ---- one message-passing step (conv MFMA + GRU), device body ----
static __device__ __forceinline__ void step_body(
    const unsigned short* __restrict__ xb_in, const float* __restrict__ h_in,
    float* __restrict__ h_out, unsigned short* __restrict__ xb_out,
    const unsigned short* __restrict__ WeTn, const float* __restrict__ conv_b,
    const unsigned short* __restrict__ gWb,
    const float* __restrict__ gbih, const float* __restrict__ gbhh,
    unsigned short* cvp, int wv, int cl, int kg, int bsel, int n0,
    const int srcs[4][4]) {

    f32x4 a[4][2] = {};
#pragma unroll
    for (int u = 0; u < 4; ++u) {
        const unsigned short* wp = WeTn + ((size_t)(n0 + wv * 4 + u) * 4) * HH;
        s16x8 af[4][2];
#pragma unroll
        for (int d = 0; d < 4; ++d) {
            af[d][0] = *(const s16x8*)(wp + d * HH + cl * 32 + kg * 8);
            af[d][1] = *(const s16x8*)(wp + d * HH + 512 + cl * 32 + kg * 8);
        }
#pragma unroll
        for (int d = 0; d < 4; ++d) {
            s16x8 bfr = *(const s16x8*)(xb_in + ((size_t)(bsel * NN + srcs[u][d])) * 32 + kg * 8);
            a[u][0] = __builtin_amdgcn_mfma_f32_16x16x32_bf16(af[d][0], bfr, a[u][0], 0, 0, 0);
            a[u][1] = __builtin_amdgcn_mfma_f32_16x16x32_bf16(af[d][1], bfr, a[u][1], 0, 0, 0);
        }
    }

    f32x4 cb0 = *(const f32x4*)(conv_b + kg * 4);
    f32x4 cb1 = *(const f32x4*)(conv_b + 16 + kg * 4);
    if (cl < 2) {                  // batch = cl; rows o = kg*4+r / 16+kg*4+r
#pragma unroll
        for (int u = 0; u < 4; ++u) {
            int nl = wv * 4 + u;
            unsigned* cp32 = (unsigned*)(cvp + (cl * 16 + nl) * 32);
            cp32[kg * 2]     = packbf(fmaxf(a[u][0][0] + cb0[0], 0.f), fmaxf(a[u][0][1] + cb0[1], 0.f));
            cp32[kg * 2 + 1] = packbf(fmaxf(a[u][0][2] + cb0[2], 0.f), fmaxf(a[u][0][3] + cb0[3], 0.f));
            cp32[8 + kg * 2]     = packbf(fmaxf(a[u][1][0] + cb1[0], 0.f), fmaxf(a[u][1][1] + cb1[1], 0.f));
            cp32[8 + kg * 2 + 1] = packbf(fmaxf(a[u][1][2] + cb1[2], 0.f), fmaxf(a[u][1][3] + cb1[3], 0.f));
        }
    }
    __syncthreads();

    // GRU: waves 0/1 = batch 0/1 (16 m-rows each)
    if (wv < 2) {
        const size_t mbase = (size_t)wv * NN + n0;

        s16x8 ax = *(const s16x8*)(cvp + (wv * 16 + cl) * 32 + kg * 8);
        s16x8 ah = *(const s16x8*)(xb_in + (mbase + cl) * 32 + kg * 8);

        f32x4 accx[6], acch[6];
#pragma unroll
        for (int jb = 0; jb < 6; ++jb) {
            s16x8 wx = *(const s16x8*)(gWb + (jb * 16 + cl) * 32 + kg * 8);
            s16x8 wh = *(const s16x8*)(gWb + 3072 + (jb * 16 + cl) * 32 + kg * 8);
            f32x4 z0 = {};
            f32x4 z1 = {};
            accx[jb] = __builtin_amdgcn_mfma_f32_16x16x32_bf16(ax, wx, z0, 0, 0, 0);
            acch[jb] = __builtin_amdgcn_mfma_f32_16x16x32_bf16(ah, wh, z1, 0, 0, 0);
        }

        float bihR[2] = {gbih[cl],      gbih[16 + cl]};
        float bihZ[2] = {gbih[32 + cl], gbih[48 + cl]};
        float bihN[2] = {gbih[64 + cl], gbih[80 + cl]};
        float bhhR[2] = {gbhh[cl],      gbhh[16 + cl]};
        float bhhZ[2] = {gbhh[32 + cl], gbhh[48 + cl]};
        float bhhN[2] = {gbhh[64 + cl], gbhh[80 + cl]};

#pragma unroll
        for (int hb = 0; hb < 2; ++hb) {
            const float* hp = h_in  + mbase * 32 + kg * 128 + hb * 16 + cl;
            float*       op = h_out + mbase * 32 + kg * 128 + hb * 16 + cl;
            unsigned short* xp = xb_out + mbase * 32 + kg * 128 + hb * 16 + cl;
#pragma unroll
            for (int ri = 0; ri < 4; ++ri) {
                float rg = sigf(accx[hb][ri] + acch[hb][ri] + bihR[hb] + bhhR[hb]);
                float zg = sigf(accx[2 + hb][ri] + acch[2 + hb][ri] + bihZ[hb] + bhhZ[hb]);
                float ng = tanhfast((accx[4 + hb][ri] + bihN[hb]) +
                                    rg * (acch[4 + hb][ri] + bhhN[hb]));
                float ho = hp[ri * 32];
                float hn = fmaf(zg, ho - ng, ng);
                op[ri * 32] = hn;
                xp[ri * 32] = f2bf(hn);
            }
        }
    }
}

static __device__ __forceinline__ void calc_srcs(int n0, int wv, int srcs[4][4]) {
    const int tt = n0 / TILE;
#pragma unroll
    for (int u = 0; u < 4; ++u) {
        int n = n0 + wv * 4 + u;
        int i = n - tt * TILE;
        int r = i / NXC;
        int c = i - r * NXC;
        int bt = tt * TILE;
        int rm = (r == 0) ? NXC - 1 : r - 1;
        int rp = (r == NXC - 1) ? 0 : r + 1;
        int cm = (c == 0) ? NXC - 1 : c - 1;
        int cp = (c == NXC - 1) ? 0 : c + 1;
        srcs[u][0] = bt + rm * NXC + c;
        srcs[u][1] = bt + rp * NXC + c;
        srcs[u][2] = bt + r * NXC + cm;
        srcs[u][3] = bt + r * NXC + cp;
    }
}

// ---- all 4 steps in one cooperative kernel; grid.sync between steps ----
__global__ void __launch_bounds__(256, 4)
k_steps(unsigned short* xb0, unsigned short* xb1,
        float* S0, float* S1, float* out,
        const unsigned short* __restrict__ WeTn, const float* __restrict__ conv_b,
        const unsigned short* __restrict__ gWb,
        const float* __restrict__ gbih, const float* __restrict__ gbhh) {
    cg::grid_group grid = cg::this_grid();
    __shared__ unsigned short cv[2 * 16 * 32];      // 2KB conv staging

    const int tid  = threadIdx.x;
    const int wv   = tid >> 6;
    const int l    = tid & 63;
    const int cl   = l & 15;
    const int kg   = l >> 4;
    const int bsel = cl & 1;
    const int n0   = blockIdx.x * 16;

    int srcs[4][4];
    calc_srcs(n0, wv, srcs);

    step_body(xb0, S0, S1, xb1, WeTn, conv_b, gWb, gbih, gbhh,
              cv, wv, cl, kg, bsel, n0, srcs);
    grid.sync();
    step_body(xb1, S1, S0, xb0, WeTn, conv_b, gWb, gbih, gbhh,
              cv, wv, cl, kg, bsel, n0, srcs);
    grid.sync();
    step_body(xb0, S0, S1, xb1, WeTn, conv_b, gWb, gbih, gbhh,
              cv, wv, cl, kg, bsel, n0, srcs);
    grid.sync();
    step_body(xb1, S1, out, xb0, WeTn, conv_b, gWb, gbih, gbhh,
              cv, wv, cl, kg, bsel, n0, srcs);
}

// ---- fallback: one step per launch (identical math) ----
__global__ void __launch_bounds__(256, 4)
k_step1(const unsigned short* __restrict__ xb_in, const float* __restrict__ h_in,
        float* __restrict__ h_out, unsigned short* __restrict__ xb_out,
        const unsigned short* __restrict__ WeTn, const float* __restrict__ conv_b,
        const unsigned short* __restrict__ gWb,
        const float* __restrict__ gbih, const float* __restrict__ gbhh) {
    __shared__ unsigned short cv[2 * 16 * 32];
    const int tid  = threadIdx.x;
    const int wv   = tid >> 6;
    const int l    = tid & 63;
    const int cl   = l & 15;
    const int kg   = l >> 4;
    const int bsel = cl & 1;
    const int n0   = blockIdx.x * 16;

    int srcs[4][4];
    calc_srcs(n0, wv, srcs);
    step_body(xb_in, h_in, h_out, xb_out, WeTn, conv_b, gWb, gbih, gbhh,
              cv, wv, cl, kg, bsel, n0, srcs);
}

extern "C" void kernel_launch(void* const* d_in, const int* in_sizes, int n_in,
                              void* d_out, int out_size, void* d_ws, size_t ws_size,
                              hipStream_t stream) {
    const float* in_nodes = (const float*)d_in[0];
    const float* ef       = (const float*)d_in[1];
    const float* pW1      = (const float*)d_in[4];
    const float* pb1      = (const float*)d_in[5];
    const float* pW2      = (const float*)d_in[6];
    const float* pb2      = (const float*)d_in[7];
    const float* eW1      = (const float*)d_in[8];
    const float* eb1      = (const float*)d_in[9];
    const float* eW2      = (const float*)d_in[10];
    const float* eb2      = (const float*)d_in[11];
    const float* convb    = (const float*)d_in[12];
    const float* gWih     = (const float*)d_in[13];
    const float* gWhh     = (const float*)d_in[14];
    const float* gbih     = (const float*)d_in[15];
    const float* gbhh     = (const float*)d_in[16];

    unsigned char* ws = (unsigned char*)d_ws;
    unsigned short* WeTn = (unsigned short*)(ws + 0ull);          // 113246208 B
    unsigned short* aB   = (unsigned short*)(ws + 113246208ull);  //   7077888 B
    unsigned short* BpT  = (unsigned short*)(ws + 120324096ull);  //    131072 B
    float*          eb2p = (float*)         (ws + 120455168ull);  //      4096 B
    float*          S0   = (float*)         (ws + 120459264ull);  //   3538944 B
    float*          S1   = (float*)         (ws + 123998208ull);  //   3538944 B
    unsigned short* xb0  = (unsigned short*)(ws + 127537152ull);  //   1769472 B
    unsigned short* xb1  = (unsigned short*)(ws + 129306624ull);  //   1769472 B
    unsigned short* gWb  = (unsigned short*)(ws + 131076096ull);  //     12288 B

    k_pre<<<7000, 256, 0, stream>>>(ef, eW1, eb1, aB, eW2, eb2, BpT, eb2p,
                                    in_nodes, pW1, pb1, pW2, pb2, S0, xb0,
                                    gWih, gWhh, gWb);
    dim3 g3(8, 432);
    k_gemm<<<g3, 256, 0, stream>>>(BpT, aB, eb2p, WeTn);

    float* out = (float*)d_out;
    void* args[] = {&xb0, &xb1, &S0, &S1, &out, &WeTn, &convb, &gWb, &gbih, &gbhh};
    hipError_t err = hipLaunchCooperativeKernel((void*)k_steps, dim3(864), dim3(256),
                                                args, 0, stream);
    if (err != hipSuccess) {
        // deterministic fallback: 4 separate step launches (same math)
        k_step1<<<NN / 16, 256, 0, stream>>>(xb0, S0, S1, xb1, WeTn, convb, gWb, gbih, gbhh);
        k_step1<<<NN / 16, 256, 0, stream>>>(xb1, S1, S0, xb0, WeTn, convb, gWb, gbih, gbhh);
        k_step1<<<NN / 16, 256, 0, stream>>>(xb0, S0, S1, xb1, WeTn, convb, gWb, gbih, gbhh);
        k_step1<<<NN / 16, 256, 0, stream>>>(xb1, S1, out, xb0, WeTn, convb, gWb, gbih, gbhh);
    }
}

// Round 12
// 231.751 us; speedup vs baseline: 2.4405x; 2.4405x over previous
//
#include <hip/hip_runtime.h>
#include <stdint.h>

// ---- problem constants (fixed by setup_inputs) ----
constexpr int NB   = 2;       // batch
constexpr int NN   = 13824;   // nodes = 6*48*48
constexpr int NE   = 55296;   // edges = 4*NN
constexpr int H    = 32;      // node hidden
constexpr int EHID = 64;      // edge hidden
constexpr int HH   = 1024;    // H*H
constexpr int TILE = 2304;    // 48*48 nodes per tile
constexpr int NXC  = 48;

typedef float f32x4 __attribute__((ext_vector_type(4)));
typedef short s16x8 __attribute__((ext_vector_type(8)));
typedef unsigned int u32x2 __attribute__((ext_vector_type(2)));
typedef unsigned int u32x4 __attribute__((ext_vector_type(4)));
typedef __attribute__((address_space(1))) unsigned int as1_uint;
typedef __attribute__((address_space(3))) unsigned int as3_uint;

static __device__ __forceinline__ unsigned short f2bf(float f) {
    unsigned u = __float_as_uint(f);
    return (unsigned short)((u + 0x7fffu + ((u >> 16) & 1u)) >> 16);
}
static __device__ __forceinline__ unsigned packbf(float lo, float hi) {
    return (unsigned)f2bf(lo) | ((unsigned)f2bf(hi) << 16);
}
static __device__ __forceinline__ float sigf(float v) {
    return 1.0f / (1.0f + __expf(-v));
}
static __device__ __forceinline__ float tanhfast(float v) {
    return 1.0f - 2.0f / (1.0f + __expf(2.0f * v));
}

// ---- fused pre-pass: aB | BpT | node projection | GRU weight bf16 ----
__global__ void __launch_bounds__(256)
k_pre(const float* __restrict__ ef, const float* __restrict__ eW1,
      const float* __restrict__ eb1, unsigned short* __restrict__ aB,
      const float* __restrict__ eW2, const float* __restrict__ eb2,
      unsigned short* __restrict__ BpT, float* __restrict__ eb2p,
      const float* __restrict__ in, const float* __restrict__ pW1,
      const float* __restrict__ pb1, const float* __restrict__ pW2,
      const float* __restrict__ pb2, float* __restrict__ S0,
      unsigned short* __restrict__ xb0,
      const float* __restrict__ gWih, const float* __restrict__ gWhh,
      unsigned short* __restrict__ gWb) {
    int blk = blockIdx.x;
    if (blk < 3456) {              // aB[e][k] = relu(ef@eW1+eb1) bf16, 4 k per thread
        int t = blk * 256 + threadIdx.x;
        int e = t >> 4, kq = (t & 15) * 4;
        float f0 = ef[e * 2], f1 = ef[e * 2 + 1];
        u32x2 w;
#pragma unroll
        for (int q = 0; q < 2; q++) {
            int k = kq + q * 2;
            float v0 = fmaxf(f0 * eW1[k]     + f1 * eW1[64 + k]     + eb1[k],     0.f);
            float v1 = fmaxf(f0 * eW1[k + 1] + f1 * eW1[64 + k + 1] + eb1[k + 1], 0.f);
            w[q] = packbf(v0, v1);
        }
        *(u32x2*)(aB + e * 64 + kq) = w;
    } else if (blk < 3520) {       // BpT[j'][k] = eW2[k][perm(j')]
        int t = (blk - 3456) * 256 + threadIdx.x;   // 16384 threads
        int jp = t >> 4, kq = (t & 15) * 4;
        int src_col = (jp & 31) * 32 + (jp >> 5);
        u32x2 w;
#pragma unroll
        for (int q = 0; q < 2; q++) {
            int k = kq + q * 2;
            w[q] = packbf(eW2[k * HH + src_col], eW2[(k + 1) * HH + src_col]);
        }
        *(u32x2*)(BpT + jp * 64 + kq) = w;
        if (kq == 0) eb2p[jp] = eb2[src_col];
    } else if (blk < 6976) {       // node projection
        int t = (blk - 3520) * 256 + threadIdx.x;
        int p = t >> 5;            // row m = b*NN + n
        int l = t & 31;
        float iv = (l < 16) ? in[p * 16 + l] : 0.f;
        float hid = pb1[l];
#pragma unroll
        for (int c = 0; c < 16; c++) hid = fmaf(__shfl(iv, c, 32), pW1[c * H + l], hid);
        hid = fmaxf(hid, 0.f);
        float out = pb2[l];
#pragma unroll
        for (int h = 0; h < 32; h++) out = fmaf(__shfl(hid, h, 32), pW2[h * H + l], out);
        S0[p * H + l]  = out;
        xb0[p * H + l] = f2bf(out);
    } else {                       // GRU weights: [96][32] Wih | [96][32] Whh
        int idx = (blk - 6976) * 256 + threadIdx.x;    // [0, 6144)
        gWb[idx] = f2bf(idx < 3072 ? gWih[idx] : gWhh[idx - 3072]);
    }
}

// ---- We GEMM: A = BpT (j' rows), B = aB (e rows) ----
// Output rows node-major WeTn[(n*4+d)], with intra-matrix XOR swizzle baked:
// byte-in-matrix = (j'*2) ^ ((o&7)<<4), o = j'>>5. (conflict-free step reads)
__global__ void __launch_bounds__(256)
k_gemm(const unsigned short* __restrict__ Bp, const unsigned short* __restrict__ Ae,
       const float* __restrict__ eb2p, unsigned short* __restrict__ C) {
    __shared__ unsigned char lds[32768] __attribute__((aligned(16)));
    const int tid  = threadIdx.x;
    const int wv   = tid >> 6;
    const int lane = tid & 63;
    const int lr   = lane & 15;
    const int lg   = lane >> 4;
    const int jbt  = blockIdx.x;  // j' tile 0..7
    const int ebt  = blockIdx.y;  // e tile 0..431

    const unsigned char* Ag = (const unsigned char*)Bp + (size_t)jbt * 16384;
    const unsigned char* Bg = (const unsigned char*)Ae + (size_t)ebt * 16384;

#pragma unroll
    for (int c = 0; c < 4; c++) {
        int fbase = (wv * 4 + c) * 1024;
        int f  = fbase + lane * 16;
        int sw = f ^ (((f >> 7) & 7) << 4);
        __builtin_amdgcn_global_load_lds((const as1_uint*)(Ag + sw),
                                         (as3_uint*)(lds + fbase), 16, 0, 0);
        __builtin_amdgcn_global_load_lds((const as1_uint*)(Bg + sw),
                                         (as3_uint*)(lds + 16384 + fbase), 16, 0, 0);
    }
    asm volatile("s_waitcnt vmcnt(0)" ::: "memory");
    __syncthreads();

    const int wm = wv >> 1, wn = wv & 1;
    f32x4 acc[4][4] = {};
#pragma unroll
    for (int kk = 0; kk < 2; kk++) {
        s16x8 af[4], bf[4];
#pragma unroll
        for (int i = 0; i < 4; i++) {
            int la = ((wm * 64 + i * 16 + lr) * 64 + kk * 32 + lg * 8) * 2;
            la ^= ((la >> 7) & 7) << 4;
            af[i] = *(const s16x8*)(lds + la);
            int lb = ((wn * 64 + i * 16 + lr) * 64 + kk * 32 + lg * 8) * 2;
            lb ^= ((lb >> 7) & 7) << 4;
            bf[i] = *(const s16x8*)(lds + 16384 + lb);
        }
#pragma unroll
        for (int i = 0; i < 4; i++)
#pragma unroll
            for (int j = 0; j < 4; j++)
                acc[i][j] = __builtin_amdgcn_mfma_f32_16x16x32_bf16(af[i], bf[j], acc[i][j], 0, 0, 0);
    }

    float bias[4][4];
#pragma unroll
    for (int i = 0; i < 4; i++)
#pragma unroll
        for (int r = 0; r < 4; r++)
            bias[i][r] = eb2p[jbt * 128 + wm * 64 + i * 16 + lg * 4 + r];

    __syncthreads();   // reuse lds as C tile [e_local 128][j' 128] bf16
#pragma unroll
    for (int i = 0; i < 4; i++) {
#pragma unroll
        for (int j = 0; j < 4; j++) {
            int el    = wn * 64 + j * 16 + lr;
            int jbase = wm * 64 + i * 16 + lg * 4;
            int L0 = el * 256 + jbase * 2;
            int ph = L0 ^ ((el & 7) << 4);
            u32x2 w;
            w[0] = packbf(acc[i][j][0] + bias[i][0], acc[i][j][1] + bias[i][1]);
            w[1] = packbf(acc[i][j][2] + bias[i][2], acc[i][j][3] + bias[i][3]);
            *(u32x2*)(lds + ph) = w;
        }
    }
    __syncthreads();

    // node-major permuted + swizzled write: e = q*TILE + i0 + el, q = t*4+d
    const int q  = (ebt * 128) / TILE;      // TILE = 18*128
    const int i0 = (ebt * 128) % TILE;
    const int tt = q >> 2, dd = q & 3;
    const size_t nbase = (size_t)tt * TILE + i0;
#pragma unroll
    for (int pass = 0; pass < 8; pass++) {
        int L2 = pass * 4096 + tid * 16;
        int el = L2 >> 8;
        int ph = L2 ^ ((el & 7) << 4);
        u32x4 v = *(const u32x4*)(lds + ph);
        size_t drow = (nbase + el) * 4 + dd;
        int jg = jbt * 128 + ((L2 & 255) >> 1);   // j' global of this 16B chunk
        int lb = (jg * 2) ^ (((jg >> 5) & 7) << 4);
        *(u32x4*)((unsigned char*)C + drow * 2048 + lb) = v;
    }
}

// ---- step kernel: async-stage 64KB WeT chunk -> LDS, conv MFMA, GRU ----
// 8 nodes/block; WeTnS node-major (8KB/node) with intra-matrix swizzle.
__global__ void __launch_bounds__(256)
k_stepB(const unsigned short* __restrict__ xb_in,   // [2][NN][32] bf16
        const float* __restrict__ h_in,             // [2][NN][32] f32
        const unsigned char* __restrict__ WeTnS,    // swizzled node-major We
        const float* __restrict__ conv_b,
        const unsigned short* __restrict__ gWb,     // [96][32] Wih | [96][32] Whh
        const float* __restrict__ gbih, const float* __restrict__ gbhh,
        float* __restrict__ h_out, unsigned short* __restrict__ xb_out) {
    __shared__ unsigned char stage[65536 + 1024] __attribute__((aligned(16)));
    unsigned short* cvp = (unsigned short*)(stage + 65536);   // cv[2][8][32]

    const int tid  = threadIdx.x;
    const int wv   = tid >> 6;
    const int l    = tid & 63;
    const int cl   = l & 15;
    const int kg   = l >> 4;
    const int bsel = cl & 1;
    const int n0   = blockIdx.x * 8;
    const int tt   = n0 / TILE;

    // ---- async stage: 64KB contiguous, 16 fire-and-forget loads/thread ----
    const unsigned char* gsrc = WeTnS + (size_t)n0 * 8192;
#pragma unroll
    for (int i = 0; i < 16; i++) {
        int off = wv * 16384 + i * 1024 + (l << 4);
        __builtin_amdgcn_global_load_lds((const as1_uint*)(gsrc + off),
                                         (as3_uint*)(stage + off), 16, 0, 0);
    }

    // neighbor indices for this wave's 2 nodes (overlaps with loads in flight)
    int srcs[2][4];
#pragma unroll
    for (int u = 0; u < 2; ++u) {
        int n = n0 + wv * 2 + u;
        int i = n - tt * TILE;
        int r = i / NXC;
        int c = i - r * NXC;
        int bt = tt * TILE;
        int rm = (r == 0) ? NXC - 1 : r - 1;
        int rp = (r == NXC - 1) ? 0 : r + 1;
        int cm = (c == 0) ? NXC - 1 : c - 1;
        int cp = (c == NXC - 1) ? 0 : c + 1;
        srcs[u][0] = bt + rm * NXC + c;
        srcs[u][1] = bt + rp * NXC + c;
        srcs[u][2] = bt + r * NXC + cm;
        srcs[u][3] = bt + r * NXC + cp;
    }
    // x B-fragments (global, L2/L3-resident)
    s16x8 bfr[2][4];
#pragma unroll
    for (int u = 0; u < 2; ++u)
#pragma unroll
        for (int d = 0; d < 4; ++d)
            bfr[u][d] = *(const s16x8*)(xb_in + ((size_t)(bsel * NN + srcs[u][d])) * 32 + kg * 8);

    asm volatile("s_waitcnt vmcnt(0)" ::: "memory");
    __syncthreads();

    // ---- conv: A from LDS (swizzled, conflict-free), 2 nodes/wave ----
    const int lb0 = (cl * 64 + kg * 16) ^ ((cl & 7) << 4);          // o = cl
    const int lb1 = (1024 + cl * 64 + kg * 16) ^ ((cl & 7) << 4);   // o = 16+cl
    f32x4 a[2][2] = {};
#pragma unroll
    for (int u = 0; u < 2; ++u) {
        const unsigned char* np = stage + (wv * 2 + u) * 8192;
#pragma unroll
        for (int d = 0; d < 4; ++d) {
            s16x8 af0 = *(const s16x8*)(np + d * 2048 + lb0);
            s16x8 af1 = *(const s16x8*)(np + d * 2048 + lb1);
            a[u][0] = __builtin_amdgcn_mfma_f32_16x16x32_bf16(af0, bfr[u][d], a[u][0], 0, 0, 0);
            a[u][1] = __builtin_amdgcn_mfma_f32_16x16x32_bf16(af1, bfr[u][d], a[u][1], 0, 0, 0);
        }
    }

    f32x4 cb0 = *(const f32x4*)(conv_b + kg * 4);
    f32x4 cb1 = *(const f32x4*)(conv_b + 16 + kg * 4);
    if (cl < 2) {                  // batch = cl; rows o = kg*4+r / 16+kg*4+r
#pragma unroll
        for (int u = 0; u < 2; ++u) {
            int nl = wv * 2 + u;
            unsigned* cp32 = (unsigned*)(cvp + (cl * 8 + nl) * 32);
            cp32[kg * 2]     = packbf(fmaxf(a[u][0][0] + cb0[0], 0.f), fmaxf(a[u][0][1] + cb0[1], 0.f));
            cp32[kg * 2 + 1] = packbf(fmaxf(a[u][0][2] + cb0[2], 0.f), fmaxf(a[u][0][3] + cb0[3], 0.f));
            cp32[8 + kg * 2]     = packbf(fmaxf(a[u][1][0] + cb1[0], 0.f), fmaxf(a[u][1][1] + cb1[1], 0.f));
            cp32[8 + kg * 2 + 1] = packbf(fmaxf(a[u][1][2] + cb1[2], 0.f), fmaxf(a[u][1][3] + cb1[3], 0.f));
        }
    }
    __syncthreads();

    // ---- GRU: wave 0; m-row r=cl -> (b=r>>3, nl=r&7) ----
    if (wv == 0) {
        s16x8 ax = *(const s16x8*)(cvp + ((cl >> 3) * 8 + (cl & 7)) * 32 + kg * 8);
        s16x8 ah = *(const s16x8*)(xb_in + ((size_t)(cl >> 3) * NN + n0 + (cl & 7)) * 32 + kg * 8);

        f32x4 accx[6], acch[6];
#pragma unroll
        for (int jb = 0; jb < 6; ++jb) {
            s16x8 wx = *(const s16x8*)(gWb + (jb * 16 + cl) * 32 + kg * 8);
            s16x8 wh = *(const s16x8*)(gWb + 3072 + (jb * 16 + cl) * 32 + kg * 8);
            f32x4 z0 = {};
            f32x4 z1 = {};
            accx[jb] = __builtin_amdgcn_mfma_f32_16x16x32_bf16(ax, wx, z0, 0, 0, 0);
            acch[jb] = __builtin_amdgcn_mfma_f32_16x16x32_bf16(ah, wh, z1, 0, 0, 0);
        }

        float bihR[2] = {gbih[cl],      gbih[16 + cl]};
        float bihZ[2] = {gbih[32 + cl], gbih[48 + cl]};
        float bihN[2] = {gbih[64 + cl], gbih[80 + cl]};
        float bhhR[2] = {gbhh[cl],      gbhh[16 + cl]};
        float bhhZ[2] = {gbhh[32 + cl], gbhh[48 + cl]};
        float bhhN[2] = {gbhh[64 + cl], gbhh[80 + cl]};

#pragma unroll
        for (int hb = 0; hb < 2; ++hb) {
#pragma unroll
            for (int ri = 0; ri < 4; ++ri) {
                int rrow = kg * 4 + ri;              // m-row -> (b, nl)
                size_t m = (size_t)(rrow >> 3) * NN + n0 + (rrow & 7);
                float rg = sigf(accx[hb][ri] + acch[hb][ri] + bihR[hb] + bhhR[hb]);
                float zg = sigf(accx[2 + hb][ri] + acch[2 + hb][ri] + bihZ[hb] + bhhZ[hb]);
                float ng = tanhfast((accx[4 + hb][ri] + bihN[hb]) +
                                    rg * (acch[4 + hb][ri] + bhhN[hb]));
                float ho = h_in[m * 32 + hb * 16 + cl];
                float hn = fmaf(zg, ho - ng, ng);
                h_out[m * 32 + hb * 16 + cl]  = hn;
                xb_out[m * 32 + hb * 16 + cl] = f2bf(hn);
            }
        }
    }
}

extern "C" void kernel_launch(void* const* d_in, const int* in_sizes, int n_in,
                              void* d_out, int out_size, void* d_ws, size_t ws_size,
                              hipStream_t stream) {
    const float* in_nodes = (const float*)d_in[0];
    const float* ef       = (const float*)d_in[1];
    const float* pW1      = (const float*)d_in[4];
    const float* pb1      = (const float*)d_in[5];
    const float* pW2      = (const float*)d_in[6];
    const float* pb2      = (const float*)d_in[7];
    const float* eW1      = (const float*)d_in[8];
    const float* eb1      = (const float*)d_in[9];
    const float* eW2      = (const float*)d_in[10];
    const float* eb2      = (const float*)d_in[11];
    const float* convb    = (const float*)d_in[12];
    const float* gWih     = (const float*)d_in[13];
    const float* gWhh     = (const float*)d_in[14];
    const float* gbih     = (const float*)d_in[15];
    const float* gbhh     = (const float*)d_in[16];

    unsigned char* ws = (unsigned char*)d_ws;
    unsigned char*  WeTnS = (unsigned char*) (ws + 0ull);         // 113246208 B
    unsigned short* aB   = (unsigned short*)(ws + 113246208ull);  //   7077888 B
    unsigned short* BpT  = (unsigned short*)(ws + 120324096ull);  //    131072 B
    float*          eb2p = (float*)         (ws + 120455168ull);  //      4096 B
    float*          S0   = (float*)         (ws + 120459264ull);  //   3538944 B
    float*          S1   = (float*)         (ws + 123998208ull);  //   3538944 B
    unsigned short* xb0  = (unsigned short*)(ws + 127537152ull);  //   1769472 B
    unsigned short* xb1  = (unsigned short*)(ws + 129306624ull);  //   1769472 B
    unsigned short* gWb  = (unsigned short*)(ws + 131076096ull);  //     12288 B

    k_pre<<<7000, 256, 0, stream>>>(ef, eW1, eb1, aB, eW2, eb2, BpT, eb2p,
                                    in_nodes, pW1, pb1, pW2, pb2, S0, xb0,
                                    gWih, gWhh, gWb);
    dim3 g3(8, 432);
    k_gemm<<<g3, 256, 0, stream>>>(BpT, aB, eb2p, (unsigned short*)WeTnS);

    float* out = (float*)d_out;
    k_stepB<<<NN / 8, 256, 0, stream>>>(xb0, S0, WeTnS, convb, gWb, gbih, gbhh, S1, xb1);
    k_stepB<<<NN / 8, 256, 0, stream>>>(xb1, S1, WeTnS, convb, gWb, gbih, gbhh, S0, xb0);
    k_stepB<<<NN / 8, 256, 0, stream>>>(xb0, S0, WeTnS, convb, gWb, gbih, gbhh, S1, xb1);
    k_stepB<<<NN / 8, 256, 0, stream>>>(xb1, S1, WeTnS, convb, gWb, gbih, gbhh, out, xb0);
}